// Round 1
// 221.292 us; speedup vs baseline: 1.0195x; 1.0195x over previous
//
#include <hip/hip_runtime.h>

// DHSMoEDetector: N=16384 tokens, D=768, H=768, C=2, E=20
#define N_D 768
#define N_H 768
#define N_C 2
#define N_E 20
#define MT 128
#define NT 128
#define BK 32
#define KT (N_D / BK)
#define MAX_TILES 160
#define NCOL (N_H / NT)  // 6 column blocks
#define ROWB (N_D * 2)   // row stride in bytes (bf16)

typedef __attribute__((ext_vector_type(8))) short short8;
typedef __attribute__((ext_vector_type(4))) float f32x4;

__device__ __forceinline__ unsigned short f2bf(float f) {
  unsigned u = __builtin_bit_cast(unsigned, f);
  u += 0x7FFFu + ((u >> 16) & 1u);
  return (unsigned short)(u >> 16);
}

#define GLD_LDS16(gp, lp)                                                        \
  __builtin_amdgcn_global_load_lds(                                              \
      (const __attribute__((address_space(1))) void*)(gp),                       \
      (__attribute__((address_space(3))) void*)(lp), 16, 0, 0)

// ---------------- sort-by-expert ----------------

__global__ __launch_bounds__(256) void k_hist(const int* __restrict__ cidx,
                                              int* __restrict__ counts, int n) {
  __shared__ int lc[N_E];
  if (threadIdx.x < N_E) lc[threadIdx.x] = 0;
  __syncthreads();
  for (int i = blockIdx.x * blockDim.x + threadIdx.x; i < n;
       i += gridDim.x * blockDim.x) {
    int e = cidx[i];
    e = e < 0 ? 0 : (e >= N_E ? N_E - 1 : e);
    atomicAdd(&lc[e], 1);
  }
  __syncthreads();
  if (threadIdx.x < N_E) atomicAdd(&counts[threadIdx.x], lc[threadIdx.x]);
}

__global__ void k_scan(const int* __restrict__ counts, int* __restrict__ offsets,
                       int* __restrict__ cursor, int* __restrict__ tiles,
                       int* __restrict__ numTiles) {
  if (threadIdx.x == 0) {
    int run = 0, t = 0;
    for (int e = 0; e < N_E; ++e) {
      offsets[e] = run;
      cursor[e] = run;
      int nt = (counts[e] + MT - 1) / MT;
      for (int m = 0; m < nt && t < MAX_TILES; ++m) tiles[t++] = (e << 8) | m;
      run += counts[e];
    }
    *numTiles = t;
  }
}

// ---------------- fused scatter + gather (fp32 -> bf16, sorted order) ------
// 64 tokens per block: phase 1 claims positions via LDS hist + cursor atomics,
// phase 2 copies rows wave-per-row (3x float4 per lane). Last block zeroes the
// MT pad rows so GEMM tail tiles read zeros.

#define SG_TOK 64

__global__ __launch_bounds__(256) void k_scatter_gather(
    const int* __restrict__ cidx, int* __restrict__ cursor,
    int* __restrict__ sorted, const float* __restrict__ emb,
    unsigned short* __restrict__ Xg, int n) {
  __shared__ int lc[N_E];
  __shared__ int lbase[N_E];
  __shared__ int pos_s[SG_TOK];
  const int tid = threadIdx.x;
  const int nb = (n + SG_TOK - 1) / SG_TOK;
  if ((int)blockIdx.x >= nb) {
    // pad block: zero rows [n, n+MT)
    ushort4 z = {0, 0, 0, 0};
    ushort4* dst = (ushort4*)(Xg + (size_t)n * N_D);
    for (int k = tid; k < MT * N_D / 4; k += 256) dst[k] = z;
    return;
  }
  const int base_tok = blockIdx.x * SG_TOK;
  if (tid < N_E) lc[tid] = 0;
  __syncthreads();
  const int i = base_tok + tid;
  int e = 0, p = 0;
  if (tid < SG_TOK && i < n) {
    e = cidx[i];
    e = e < 0 ? 0 : (e >= N_E ? N_E - 1 : e);
    p = atomicAdd(&lc[e], 1);
  }
  __syncthreads();
  if (tid < N_E) lbase[tid] = atomicAdd(&cursor[tid], lc[tid]);
  __syncthreads();
  if (tid < SG_TOK) {
    if (i < n) {
      int pos = lbase[e] + p;
      sorted[pos] = i;
      pos_s[tid] = pos;
    } else {
      pos_s[tid] = -1;
    }
  }
  __syncthreads();
  const int wid = tid >> 6, lane = tid & 63;
  int nrows = n - base_tok;
  if (nrows > SG_TOK) nrows = SG_TOK;
  for (int rr = wid; rr < nrows; rr += 4) {
    const float4* s = (const float4*)(emb + (size_t)(base_tok + rr) * N_D);
    ushort4* d = (ushort4*)(Xg + (size_t)pos_s[rr] * N_D);
#pragma unroll
    for (int p2 = 0; p2 < 3; ++p2) {
      float4 v = s[lane + p2 * 64];
      ushort4 o;
      o.x = f2bf(v.x);
      o.y = f2bf(v.y);
      o.z = f2bf(v.z);
      o.w = f2bf(v.w);
      d[lane + p2 * 64] = o;
    }
  }
}

// ---------------- W1 (E,D,H) fp32 -> W1t (E,H,D) bf16, 16B stores ----------

__global__ __launch_bounds__(256) void k_w1_cvt(const float* __restrict__ W1,
                                                unsigned short* __restrict__ W1t) {
  __shared__ float tile[64][65];
  int e = blockIdx.z, h0 = blockIdx.x * 64, d0 = blockIdx.y * 64;
  const float* src = W1 + (size_t)e * N_D * N_H;
  unsigned short* dst = W1t + (size_t)e * N_H * N_D;
  int tx = threadIdx.x & 15, ty = threadIdx.x >> 4;
  for (int s = 0; s < 4; ++s) {
    int d = s * 16 + ty;
    float4 v = *(const float4*)&src[(size_t)(d0 + d) * N_H + h0 + tx * 4];
    tile[d][tx * 4 + 0] = v.x;
    tile[d][tx * 4 + 1] = v.y;
    tile[d][tx * 4 + 2] = v.z;
    tile[d][tx * 4 + 3] = v.w;
  }
  __syncthreads();
  int px = threadIdx.x & 7, py = threadIdx.x >> 3;
  for (int s = 0; s < 2; ++s) {
    int h = s * 32 + py;
    short8 v;
    for (int j = 0; j < 8; ++j)
      v[j] = (short)f2bf(tile[px * 8 + j][h]);
    *(short8*)&dst[(size_t)(h0 + h) * N_D + d0 + px * 8] = v;
  }
}

// ---------------- fused grouped GEMM1 + relu + layer2 ----------------------
// Depth-2 software pipeline with raw asm barriers: vmcnt never drains to 0
// inside the loop. LDS is chunk-major per 16-row group -> fragment
// ds_read_b128 conflict-free.
// XCD swizzle (T1, m204 bijective): each XCD owns a contiguous chunk of
// active work items, col-fastest, so the 6 col-blocks sharing an A-tile and
// the tile-rows sharing an expert's B-panels stay in one XCD's L2.

__global__ __launch_bounds__(256, 2) void k_gemm(
    const unsigned short* __restrict__ Xg, const unsigned short* __restrict__ W1t,
    const float* __restrict__ b1, const float* __restrict__ W2,
    const float* __restrict__ b2, const int* __restrict__ sorted,
    const int* __restrict__ counts, const int* __restrict__ offsets,
    const int* __restrict__ tiles, const int* __restrict__ numTiles,
    float* __restrict__ out) {
  const int nactive = *numTiles * NCOL;
  const int lin = (int)blockIdx.y * NCOL + (int)blockIdx.x;
  if (lin >= nactive) return;
  // bijective XCD remap: xcd = lin % 8 (HW round-robin heuristic) gets a
  // contiguous chunk of [0, nactive)
  const int q = nactive >> 3, r = nactive & 7;
  const int c = lin & 7, ii = lin >> 3;
  const int wgid = (c < r ? c * (q + 1) : r * (q + 1) + (c - r) * q) + ii;
  const int tileIdx = wgid / NCOL;
  const int n0 = (wgid - tileIdx * NCOL) * NT;

  const int tv = tiles[tileIdx];
  const int e = tv >> 8;
  const int m0 = (tv & 255) * MT;
  const int off = offsets[e];
  const int cnt_rel = counts[e] - m0;

  __shared__ unsigned short lA[2][MT * BK];  // 2 x 8KB, chunk-major groups
  __shared__ unsigned short lB[2][NT * BK];

  const int tid = threadIdx.x;
  const int wid = tid >> 6, lane = tid & 63;
  const int wm = (wid >> 1) * 64, wn = (wid & 1) * 64;
  const int quad = lane >> 4, lm = lane & 15;

  // staging lane mapping: row = lane&15 (+R0), k-chunk = lane>>4.
  const int R0 = wid * 32 + lm;
  const char* agp = (const char*)Xg + (size_t)(off + m0 + R0) * ROWB + quad * 16;
  const char* bgp = (const char*)W1t + (size_t)e * N_H * ROWB +
                    (size_t)(n0 + R0) * ROWB + quad * 16;
  unsigned short* lap[2] = {&lA[0][(wid * 32) * BK], &lA[1][(wid * 32) * BK]};
  unsigned short* lbp[2] = {&lB[0][(wid * 32) * BK], &lB[1][(wid * 32) * BK]};

#define ISSUE_BATCH(kk, b)                                                       \
  do {                                                                           \
    const char* a_ = agp + (kk)*64;                                              \
    const char* b_ = bgp + (kk)*64;                                              \
    GLD_LDS16(a_, lap[b]);                                                       \
    GLD_LDS16(a_ + 16 * ROWB, lap[b] + 16 * BK);                                 \
    GLD_LDS16(b_, lbp[b]);                                                       \
    GLD_LDS16(b_ + 16 * ROWB, lbp[b] + 16 * BK);                                 \
  } while (0)

  f32x4 acc[4][4] = {};

  ISSUE_BATCH(0, 0);
  ISSUE_BATCH(1, 1);

  // fragment addresses (chunk-major): row m=wm+i*16+lm, chunk=quad
  const int fa = quad * 128 + lm * 8;

  for (int kt = 0; kt < KT; ++kt) {
    const int cur = kt & 1;
    asm volatile("s_waitcnt vmcnt(4)\n\ts_barrier" ::: "memory");
    short8 af[4], bfr[4];
    for (int i = 0; i < 4; ++i)
      af[i] = *(const short8*)&lA[cur][((wm >> 4) + i) * 512 + fa];
    for (int j = 0; j < 4; ++j)
      bfr[j] = *(const short8*)&lB[cur][((wn >> 4) + j) * 512 + fa];
    asm volatile("s_waitcnt lgkmcnt(0)\n\ts_barrier" ::: "memory");
    int kk = kt + 2;
    if (kk >= KT) kk -= KT;  // dummy re-load keeps vmcnt bookkeeping uniform
    ISSUE_BATCH(kk, cur);
    for (int i = 0; i < 4; ++i)
      for (int j = 0; j < 4; ++j)
        acc[i][j] =
            __builtin_amdgcn_mfma_f32_16x16x32_bf16(af[i], bfr[j], acc[i][j], 0, 0, 0);
  }

  // ---- fused epilogue: h = relu(acc + b1), y-partial = h * W2[e] ----
  // C/D layout: col = lane&15 (lm), row = quad*4 + reg
  float y0[4][4], y1[4][4];
  for (int i = 0; i < 4; ++i)
    for (int r2 = 0; r2 < 4; ++r2) y0[i][r2] = y1[i][r2] = 0.f;

  for (int j = 0; j < 4; ++j) {
    int col = n0 + wn + j * 16 + lm;
    float bias = b1[e * N_H + col];
    float2 w2 = *(const float2*)&W2[((size_t)e * N_H + col) * N_C];
    for (int i = 0; i < 4; ++i) {
      f32x4 a = acc[i][j];
      for (int r2 = 0; r2 < 4; ++r2) {
        float h = a[r2] + bias;
        h = h > 0.f ? h : 0.f;
        y0[i][r2] += h * w2.x;
        y1[i][r2] += h * w2.y;
      }
    }
  }
  for (int s = 1; s < 16; s <<= 1) {
    for (int i = 0; i < 4; ++i)
      for (int r2 = 0; r2 < 4; ++r2) {
        y0[i][r2] += __shfl_xor(y0[i][r2], s, 64);
        y1[i][r2] += __shfl_xor(y1[i][r2], s, 64);
      }
  }
  if (lm == 0) {
    const bool add_bias = (n0 == 0) && (wn == 0);
    float bb0 = add_bias ? b2[e * N_C + 0] : 0.f;
    float bb1 = add_bias ? b2[e * N_C + 1] : 0.f;
    for (int i = 0; i < 4; ++i) {
      for (int r2 = 0; r2 < 4; ++r2) {
        int mrel = wm + i * 16 + quad * 4 + r2;
        if (mrel < cnt_rel) {
          int token = sorted[off + m0 + mrel];
          atomicAdd(&out[(size_t)token * N_C + 0], y0[i][r2] + bb0);
          atomicAdd(&out[(size_t)token * N_C + 1], y1[i][r2] + bb1);
        }
      }
    }
  }
}

// ---------------- launch ----------------

extern "C" void kernel_launch(void* const* d_in, const int* in_sizes, int n_in,
                              void* d_out, int out_size, void* d_ws, size_t ws_size,
                              hipStream_t stream) {
  const float* emb = (const float*)d_in[0];
  const int* cidx = (const int*)d_in[1];
  const float* W1 = (const float*)d_in[2];
  const float* b1 = (const float*)d_in[3];
  const float* W2 = (const float*)d_in[4];
  const float* b2 = (const float*)d_in[5];
  float* out = (float*)d_out;
  const int n = in_sizes[1];

  char* ws = (char*)d_ws;
  int* counts = (int*)ws;
  int* offsets = (int*)(ws + 128);
  int* cursor = (int*)(ws + 256);
  int* numTiles = (int*)(ws + 384);
  int* tiles = (int*)(ws + 512);
  int* sorted = (int*)(ws + 2048);
  size_t sorted_bytes = ((size_t)n * 4 + 255) & ~(size_t)255;
  unsigned short* Xg = (unsigned short*)(ws + 2048 + sorted_bytes);
  int pcap = n + MT;  // zero-padded tail rows
  unsigned short* W1t = Xg + (size_t)pcap * N_D;

  hipMemsetAsync(d_ws, 0, 2048, stream);
  hipMemsetAsync(d_out, 0, (size_t)out_size * sizeof(float), stream);
  int nb = (n + 255) / 256;
  k_hist<<<nb, 256, 0, stream>>>(cidx, counts, n);
  k_scan<<<1, 64, 0, stream>>>(counts, offsets, cursor, tiles, numTiles);
  int nb64 = (n + SG_TOK - 1) / SG_TOK;
  k_scatter_gather<<<nb64 + 1, 256, 0, stream>>>(cidx, cursor, sorted, emb, Xg, n);
  k_w1_cvt<<<dim3(N_H / 64, N_D / 64, N_E), 256, 0, stream>>>(W1, W1t);
  k_gemm<<<dim3(NCOL, MAX_TILES), 256, 0, stream>>>(
      Xg, W1t, b1, W2, b2, sorted, counts, offsets, tiles, numTiles, out);
}

// Round 2
// 220.336 us; speedup vs baseline: 1.0240x; 1.0043x over previous
//
#include <hip/hip_runtime.h>

// DHSMoEDetector: N=16384 tokens, D=768, H=768, C=2, E=20
#define N_D 768
#define N_H 768
#define N_C 2
#define N_E 20
#define MT 128
#define NT 128
#define BK 32
#define KT (N_D / BK)  // 24
#define MAX_TILES 160
#define NCOL (N_H / NT)          // 6 column blocks
#define GROUP_ELEMS (16 * N_D)   // elems per 16-row group (chunk-major [96][16][8])

typedef __attribute__((ext_vector_type(8))) short short8;
typedef __attribute__((ext_vector_type(4))) float f32x4;

__device__ __forceinline__ unsigned short f2bf(float f) {
  unsigned u = __builtin_bit_cast(unsigned, f);
  u += 0x7FFFu + ((u >> 16) & 1u);
  return (unsigned short)(u >> 16);
}

// ---------------- sort-by-expert ----------------

__global__ __launch_bounds__(256) void k_hist(const int* __restrict__ cidx,
                                              int* __restrict__ counts, int n) {
  __shared__ int lc[N_E];
  if (threadIdx.x < N_E) lc[threadIdx.x] = 0;
  __syncthreads();
  for (int i = blockIdx.x * blockDim.x + threadIdx.x; i < n;
       i += gridDim.x * blockDim.x) {
    int e = cidx[i];
    e = e < 0 ? 0 : (e >= N_E ? N_E - 1 : e);
    atomicAdd(&lc[e], 1);
  }
  __syncthreads();
  if (threadIdx.x < N_E) atomicAdd(&counts[threadIdx.x], lc[threadIdx.x]);
}

// Expert regions padded to MT alignment so 16-row groups never straddle
// experts and tail tiles read zero rows (sorted pre-filled with -1).
__global__ void k_scan(const int* __restrict__ counts, int* __restrict__ offsets,
                       int* __restrict__ cursor, int* __restrict__ tiles,
                       int* __restrict__ numTiles) {
  if (threadIdx.x == 0) {
    int run = 0, t = 0;
    for (int e = 0; e < N_E; ++e) {
      offsets[e] = run;
      cursor[e] = run;
      int nt = (counts[e] + MT - 1) / MT;
      for (int m = 0; m < nt && t < MAX_TILES; ++m) tiles[t++] = (e << 8) | m;
      run += nt * MT;  // padded
    }
    *numTiles = t;
  }
}

__global__ __launch_bounds__(256) void k_scatter(const int* __restrict__ cidx,
                                                 int* __restrict__ cursor,
                                                 int* __restrict__ sorted, int n) {
  __shared__ int lc[N_E];
  __shared__ int lbase[N_E];
  int tid = threadIdx.x;
  if (tid < N_E) lc[tid] = 0;
  __syncthreads();
  int i = blockIdx.x * blockDim.x + tid;
  int e = 0, p = 0;
  if (i < n) {
    e = cidx[i];
    e = e < 0 ? 0 : (e >= N_E ? N_E - 1 : e);
    p = atomicAdd(&lc[e], 1);
  }
  __syncthreads();
  if (tid < N_E) lbase[tid] = atomicAdd(&cursor[tid], lc[tid]);
  __syncthreads();
  if (i < n) sorted[lbase[e] + p] = i;
}

// ---------------- gather into fragment-swizzled global layout --------------
// Xs[group][chunk(96)][row16(lm)][8] bf16 — a wave's A-fragment load is a
// contiguous 1KB global_load_dwordx4. Pad rows (sorted<0) written as zeros.

__global__ __launch_bounds__(256) void k_gather_sw(const float* __restrict__ emb,
                                                   const int* __restrict__ sorted,
                                                   unsigned short* __restrict__ Xs) {
  const int g = blockIdx.x;
  const int lm = threadIdx.x & 15;
  const int c0 = threadIdx.x >> 4;  // 0..15
  const int idx = sorted[g * 16 + lm];
  const bool valid = idx >= 0;
  const float* src = emb + (size_t)(valid ? idx : 0) * N_D;
  unsigned short* dst = Xs + (size_t)g * GROUP_ELEMS + lm * 8;
#pragma unroll
  for (int it = 0; it < 6; ++it) {
    int ch = c0 + 16 * it;  // chunk 0..95
    short8 v = {};
    if (valid) {
      float4 a = *(const float4*)(src + ch * 8);
      float4 b = *(const float4*)(src + ch * 8 + 4);
      v[0] = (short)f2bf(a.x);
      v[1] = (short)f2bf(a.y);
      v[2] = (short)f2bf(a.z);
      v[3] = (short)f2bf(a.w);
      v[4] = (short)f2bf(b.x);
      v[5] = (short)f2bf(b.y);
      v[6] = (short)f2bf(b.z);
      v[7] = (short)f2bf(b.w);
    }
    *(short8*)(dst + (size_t)ch * 128) = v;  // wave-contiguous 1KB
  }
}

// ---------------- W1 (E,D,H) fp32 -> fragment-swizzled bf16 ----------------
// W1s[e][group(h/16)][chunk(d/8)][lm][8]

__global__ __launch_bounds__(256) void k_w1_sw(const float* __restrict__ W1,
                                               unsigned short* __restrict__ W1s) {
  __shared__ float tile[64][65];
  int e = blockIdx.z, h0 = blockIdx.x * 64, d0 = blockIdx.y * 64;
  const float* src = W1 + (size_t)e * N_D * N_H;
  int tx = threadIdx.x & 15, ty = threadIdx.x >> 4;
#pragma unroll
  for (int s = 0; s < 4; ++s) {
    int d = s * 16 + ty;
    float4 v = *(const float4*)&src[(size_t)(d0 + d) * N_H + h0 + tx * 4];
    tile[d][tx * 4 + 0] = v.x;
    tile[d][tx * 4 + 1] = v.y;
    tile[d][tx * 4 + 2] = v.z;
    tile[d][tx * 4 + 3] = v.w;
  }
  __syncthreads();
  unsigned short* dst = W1s + (size_t)e * N_H * N_D;
  int lm = threadIdx.x & 15, u = threadIdx.x >> 4;
  int gl = u & 3, clb = u >> 2;
#pragma unroll
  for (int p = 0; p < 2; ++p) {
    int cl = clb + 4 * p;  // 0..7
    short8 v;
#pragma unroll
    for (int j = 0; j < 8; ++j)
      v[j] = (short)f2bf(tile[cl * 8 + j][gl * 16 + lm]);
    size_t o = (size_t)(h0 / 16 + gl) * GROUP_ELEMS + (size_t)(d0 / 8 + cl) * 128 +
               (size_t)lm * 8;
    *(short8*)(dst + o) = v;
  }
}

// ---------------- fused grouped GEMM1 + relu + layer2 ----------------------
// LDS-free, barrier-free: fragments load straight from the pre-swizzled
// global layout as contiguous 1KB wave loads; compiler software-pipelines
// the pure register dataflow. XCD chunk swizzle keeps panels L2-local.

__global__ __launch_bounds__(256, 3) void k_gemm(
    const unsigned short* __restrict__ Xs, const unsigned short* __restrict__ W1s,
    const float* __restrict__ b1, const float* __restrict__ W2,
    const float* __restrict__ b2, const int* __restrict__ sorted,
    const int* __restrict__ counts, const int* __restrict__ offsets,
    const int* __restrict__ tiles, const int* __restrict__ numTiles,
    float* __restrict__ out) {
  const int nactive = *numTiles * NCOL;
  const int lin = (int)blockIdx.y * NCOL + (int)blockIdx.x;
  if (lin >= nactive) return;
  const int q = nactive >> 3, r = nactive & 7;
  const int c = lin & 7, ii = lin >> 3;
  const int wgid = (c < r ? c * (q + 1) : r * (q + 1) + (c - r) * q) + ii;
  const int tileIdx = wgid / NCOL;
  const int n0 = (wgid - tileIdx * NCOL) * NT;

  const int tv = tiles[tileIdx];
  const int e = tv >> 8;
  const int m0 = (tv & 255) * MT;
  const int off = offsets[e];  // MT-aligned
  const int cnt_rel = counts[e] - m0;

  const int tid = threadIdx.x;
  const int wid = tid >> 6, lane = tid & 63;
  const int wm = (wid >> 1) * 64, wn = (wid & 1) * 64;
  const int quad = lane >> 4, lm = lane & 15;

  // fragment base: group-major layout, within group elem = kt*512 + lane*8
  const unsigned short* Ap = Xs + (size_t)(off + m0 + wm) * N_D + lane * 8;
  const unsigned short* Bp =
      W1s + (size_t)e * N_H * N_D + (size_t)(n0 + wn) * N_D + lane * 8;

  f32x4 acc[4][4] = {};
#pragma unroll
  for (int kt = 0; kt < KT; ++kt) {
    short8 af[4], bf[4];
#pragma unroll
    for (int i = 0; i < 4; ++i)
      af[i] = *(const short8*)(Ap + (size_t)i * GROUP_ELEMS + kt * 512);
#pragma unroll
    for (int j = 0; j < 4; ++j)
      bf[j] = *(const short8*)(Bp + (size_t)j * GROUP_ELEMS + kt * 512);
#pragma unroll
    for (int i = 0; i < 4; ++i)
#pragma unroll
      for (int j = 0; j < 4; ++j)
        acc[i][j] = __builtin_amdgcn_mfma_f32_16x16x32_bf16(af[i], bf[j],
                                                            acc[i][j], 0, 0, 0);
  }

  // ---- fused epilogue: h = relu(acc + b1), y-partial = h * W2[e] ----
  // C/D layout: col = lane&15 (lm), row = quad*4 + reg
  float y0[4][4], y1[4][4];
  for (int i = 0; i < 4; ++i)
    for (int r2 = 0; r2 < 4; ++r2) y0[i][r2] = y1[i][r2] = 0.f;

  for (int j = 0; j < 4; ++j) {
    int col = n0 + wn + j * 16 + lm;
    float bias = b1[e * N_H + col];
    float2 w2 = *(const float2*)&W2[((size_t)e * N_H + col) * N_C];
    for (int i = 0; i < 4; ++i) {
      f32x4 a = acc[i][j];
      for (int r2 = 0; r2 < 4; ++r2) {
        float h = a[r2] + bias;
        h = h > 0.f ? h : 0.f;
        y0[i][r2] += h * w2.x;
        y1[i][r2] += h * w2.y;
      }
    }
  }
  for (int s = 1; s < 16; s <<= 1) {
    for (int i = 0; i < 4; ++i)
      for (int r2 = 0; r2 < 4; ++r2) {
        y0[i][r2] += __shfl_xor(y0[i][r2], s, 64);
        y1[i][r2] += __shfl_xor(y1[i][r2], s, 64);
      }
  }
  if (lm == 0) {
    const bool add_bias = (n0 == 0) && (wn == 0);
    float bb0 = add_bias ? b2[e * N_C + 0] : 0.f;
    float bb1 = add_bias ? b2[e * N_C + 1] : 0.f;
    for (int i = 0; i < 4; ++i) {
      for (int r2 = 0; r2 < 4; ++r2) {
        int mrel = wm + i * 16 + quad * 4 + r2;
        if (mrel < cnt_rel) {
          int token = sorted[off + m0 + mrel];
          atomicAdd(&out[(size_t)token * N_C + 0], y0[i][r2] + bb0);
          atomicAdd(&out[(size_t)token * N_C + 1], y1[i][r2] + bb1);
        }
      }
    }
  }
}

// ---------------- launch ----------------

extern "C" void kernel_launch(void* const* d_in, const int* in_sizes, int n_in,
                              void* d_out, int out_size, void* d_ws, size_t ws_size,
                              hipStream_t stream) {
  const float* emb = (const float*)d_in[0];
  const int* cidx = (const int*)d_in[1];
  const float* W1 = (const float*)d_in[2];
  const float* b1 = (const float*)d_in[3];
  const float* W2 = (const float*)d_in[4];
  const float* b2 = (const float*)d_in[5];
  float* out = (float*)d_out;
  const int n = in_sizes[1];

  char* ws = (char*)d_ws;
  int* counts = (int*)ws;
  int* offsets = (int*)(ws + 128);
  int* cursor = (int*)(ws + 256);
  int* numTiles = (int*)(ws + 384);
  int* tiles = (int*)(ws + 512);
  int* sorted = (int*)(ws + 2048);
  const int pcap = n + N_E * MT;  // padded row capacity (multiple of 16)
  size_t sorted_bytes = ((size_t)pcap * 4 + 255) & ~(size_t)255;
  unsigned short* Xs = (unsigned short*)(ws + 2048 + sorted_bytes);
  unsigned short* W1s = Xs + (size_t)pcap * N_D;

  hipMemsetAsync(d_ws, 0, 2048, stream);
  hipMemsetAsync(sorted, 0xFF, (size_t)pcap * 4, stream);  // sorted = -1
  hipMemsetAsync(d_out, 0, (size_t)out_size * sizeof(float), stream);
  int nb = (n + 255) / 256;
  k_hist<<<nb, 256, 0, stream>>>(cidx, counts, n);
  k_scan<<<1, 64, 0, stream>>>(counts, offsets, cursor, tiles, numTiles);
  k_scatter<<<nb, 256, 0, stream>>>(cidx, cursor, sorted, n);
  k_gather_sw<<<pcap / 16, 256, 0, stream>>>(emb, sorted, Xs);
  k_w1_sw<<<dim3(N_H / 64, N_D / 64, N_E), 256, 0, stream>>>(W1, W1s);
  k_gemm<<<dim3(NCOL, MAX_TILES), 256, 0, stream>>>(
      Xs, W1s, b1, W2, b2, sorted, counts, offsets, tiles, numTiles, out);
}